// Round 5
// baseline (437.825 us; speedup 1.0000x reference)
//
#include <hip/hip_runtime.h>
#include <stdint.h>

#define N 4096
#define BM 128
#define BN 128
#define BK 64

typedef short bf16x8 __attribute__((ext_vector_type(8)));
typedef float f32x4 __attribute__((ext_vector_type(4)));

__device__ __forceinline__ unsigned short f2bf(float x) {
  union { float f; unsigned int u; } v; v.f = x;
  unsigned int u = v.u;
  unsigned int r = (u + 0x7fffu + ((u >> 16) & 1u)) >> 16;  // RNE
  return (unsigned short)r;
}

__device__ __forceinline__ void gload16(const unsigned short* g, unsigned short* l) {
  __builtin_amdgcn_global_load_lds(
      (const __attribute__((address_space(1))) unsigned int*)g,
      (__attribute__((address_space(3))) unsigned int*)l, 16, 0, 0);
}

// ---- K1: W2 fp32 -> bf16 scratch, fused c = b1 @ W2^T + b2, zero accum ----
__global__ __launch_bounds__(256) void convert_w2(const float* __restrict__ W2,
                                                  const float* __restrict__ b1,
                                                  const float* __restrict__ b2,
                                                  unsigned short* __restrict__ W2b,
                                                  float* __restrict__ c,
                                                  float* __restrict__ lb_acc,
                                                  float* __restrict__ ub_acc) {
  const int i = blockIdx.x;
  const int t = threadIdx.x;
  const float* row = W2 + (size_t)i * N;
  unsigned short* orow = W2b + (size_t)i * N;
  float dot = 0.f;
#pragma unroll
  for (int q = 0; q < 4; ++q) {
    int idx = (q * 256 + t) * 4;
    float4 w = *(const float4*)(row + idx);
    float4 b = *(const float4*)(b1 + idx);
    dot += w.x * b.x + w.y * b.y + w.z * b.z + w.w * b.w;
    ushort4 o;
    o.x = f2bf(w.x); o.y = f2bf(w.y); o.z = f2bf(w.z); o.w = f2bf(w.w);
    *(ushort4*)(orow + idx) = o;
  }
  __shared__ float red[256];
  red[t] = dot;
  __syncthreads();
  for (int s = 128; s > 0; s >>= 1) {
    if (t < s) red[t] += red[t + s];
    __syncthreads();
  }
  if (t == 0) {
    c[i] = red[0] + b2[i];
    lb_acc[i] = 0.f;   // replaces hipMemsetAsync(d_ws): gemm runs strictly after
    ub_acc[i] = 0.f;
  }
}

// ---- K2: W1 fp32 [k][j] -> bf16 W1T [j][k] (LDS tile transpose) ----
__global__ __launch_bounds__(256) void transpose_w1(const float* __restrict__ W1,
                                                    unsigned short* __restrict__ W1T) {
  __shared__ float tile[64 * 65];
  const int t = threadIdx.x;
  const int j0 = blockIdx.x * 64, k0 = blockIdx.y * 64;
#pragma unroll
  for (int s = 0; s < 4; ++s) {
    int ck = s * 256 + t;          // 0..1023
    int row = ck >> 4;             // k_local 0..63
    int col = (ck & 15) * 4;       // j_local
    float4 v = *(const float4*)(W1 + (size_t)(k0 + row) * N + j0 + col);
    float* d = &tile[row * 65 + col];
    d[0] = v.x; d[1] = v.y; d[2] = v.z; d[3] = v.w;
  }
  __syncthreads();
  int jl = t >> 2, ch = (t & 3) * 16;
  alignas(16) unsigned short outv[16];
#pragma unroll
  for (int m = 0; m < 16; ++m) outv[m] = f2bf(tile[(ch + m) * 65 + jl]);
  uint4* dst = (uint4*)(W1T + (size_t)(j0 + jl) * N + k0 + ch);
  dst[0] = *(const uint4*)&outv[0];
  dst[1] = *(const uint4*)&outv[8];
}

// ---- K3: S = W2b @ W1Tb^T (bf16 MFMA, BK=64, XOR-swizzled LDS),
//          fused sign-selected bound reductions ----
// LDS physical 16B-chunk index = row*8 + (chunk ^ (row&7)).
// Staging keeps contiguous per-wave LDS dests (global_load_lds constraint);
// only the per-lane GLOBAL chunk is XOR'd. Fragment ds_read_b128s then land
// on 2 lanes/bank-group (free) instead of 16-way conflicts.
__global__ __launch_bounds__(256, 4) void gemm_bounds(const unsigned short* __restrict__ A,  // W2b [i][k]
                                                      const unsigned short* __restrict__ B,  // W1Tb [j][k]
                                                      const float* __restrict__ lb0,
                                                      const float* __restrict__ ub0,
                                                      float* __restrict__ lb_acc,
                                                      float* __restrict__ ub_acc) {
  __shared__ unsigned short As[BM * BK];   // 16 KB
  __shared__ unsigned short Bs[BN * BK];   // 16 KB
  const int t = threadIdx.x;
  const int lane = t & 63, w = t >> 6;
  const int wm = (w >> 1) * 64, wn = (w & 1) * 64;
  const int i0 = blockIdx.y * BM, j0 = blockIdx.x * BN;
  const int quad = lane >> 4, l16 = lane & 15;
  const int s7 = l16 & 7;                  // row&7 for this lane's fragment rows

  f32x4 acc[4][4] = {};

  // staging: thread t handles physical chunk P = p*256 + t; row = P>>3,
  // physical sub-chunk P&7 holds global chunk (P&7) ^ (row&7).
  const int rstage = t >> 3;                       // + p*32 in loop (32 ≡ 0 mod 8)
  const int cstage = (t & 7) ^ (rstage & 7);
  const unsigned short* ga = A + (size_t)(i0 + rstage) * N + cstage * 8;
  const unsigned short* gb = B + (size_t)(j0 + rstage) * N + cstage * 8;

  for (int kt = 0; kt < N / BK; ++kt) {
    __syncthreads();
#pragma unroll
    for (int p = 0; p < 4; ++p)
      gload16(ga + (size_t)(p * 32) * N, &As[(p * 256 + t) * 8]);
#pragma unroll
    for (int p = 0; p < 4; ++p)
      gload16(gb + (size_t)(p * 32) * N, &Bs[(p * 256 + t) * 8]);
    __syncthreads();
#pragma unroll
    for (int h = 0; h < 2; ++h) {
      const int xoff = ((h * 4 + quad) ^ s7) * 8;  // swizzled halfword offset
      bf16x8 af[4], bfr[4];
#pragma unroll
      for (int tm = 0; tm < 4; ++tm)
        af[tm] = *(const bf16x8*)&As[(wm + tm * 16 + l16) * BK + xoff];
#pragma unroll
      for (int tn = 0; tn < 4; ++tn)
        bfr[tn] = *(const bf16x8*)&Bs[(wn + tn * 16 + l16) * BK + xoff];
#pragma unroll
      for (int tm = 0; tm < 4; ++tm)
#pragma unroll
        for (int tn = 0; tn < 4; ++tn)
          acc[tm][tn] = __builtin_amdgcn_mfma_f32_16x16x32_bf16(af[tm], bfr[tn], acc[tm][tn], 0, 0, 0);
    }
    ga += BK;
    gb += BK;
  }

  // epilogue: lbounds_i += (s>0?lb0_j:ub0_j)*s ; ubounds_i += (s>0?ub0_j:lb0_j)*s
  float lbv[4], ubv[4];
#pragma unroll
  for (int tn = 0; tn < 4; ++tn) {
    int j = j0 + wn + tn * 16 + l16;
    lbv[tn] = lb0[j];
    ubv[tn] = ub0[j];
  }
#pragma unroll
  for (int tm = 0; tm < 4; ++tm) {
#pragma unroll
    for (int r = 0; r < 4; ++r) {
      float ls = 0.f, us = 0.f;
#pragma unroll
      for (int tn = 0; tn < 4; ++tn) {
        float s = acc[tm][tn][r];
        ls += s * (s > 0.f ? lbv[tn] : ubv[tn]);
        us += s * (s > 0.f ? ubv[tn] : lbv[tn]);
      }
#pragma unroll
      for (int off = 1; off < 16; off <<= 1) {
        ls += __shfl_xor(ls, off, 64);
        us += __shfl_xor(us, off, 64);
      }
      if (l16 == 0) {
        int i = i0 + wm + tm * 16 + quad * 4 + r;
        atomicAdd(&lb_acc[i], ls);
        atomicAdd(&ub_acc[i], us);
      }
    }
  }
}

// ---- K4: fused zero-fill + DeepPolyReLU patch (single pass over 134 MB) ----
struct ReluVals { float lslope, uslope, uinter; };

__device__ __forceinline__ ReluVals relu_vals(int i,
                                              const float* __restrict__ cvec,
                                              const float* __restrict__ lb_acc,
                                              const float* __restrict__ ub_acc,
                                              const float* __restrict__ raw_alpha) {
  float cc = cvec[i];
  float lb = lb_acc[i] + cc;
  float ub = ub_acc[i] + cc;
  float alpha = 1.f / (1.f + expf(-raw_alpha[i]));
  float denom = ub - lb;
  float slope = (denom == 0.f) ? 0.f : ub / denom;
  bool below = ub <= 0.f, above = lb >= 0.f;
  bool crossing = !(below || above);
  float base = above ? 1.f : 0.f;
  ReluVals v;
  v.uslope = crossing ? slope : base;
  v.uinter = crossing ? (1.f - slope) * ub : 0.f;
  float l1 = crossing ? 0.f : base;
  float l2 = crossing ? 1.f : base;
  v.lslope = alpha * l1 + (1.f - alpha) * l2;
  return v;
}

__global__ __launch_bounds__(256) void fill_patch(float4* __restrict__ out, int n4,
                                                  const float* __restrict__ cvec,
                                                  const float* __restrict__ lb_acc,
                                                  const float* __restrict__ ub_acc,
                                                  const float* __restrict__ raw_alpha) {
  const size_t NN = (size_t)N * N;
  const size_t d1_end = NN;              // diag(lslope) region
  const size_t d2_beg = NN + N;          // diag(uslope) region (after lintercept zeros)
  const size_t d2_end = 2 * NN + N;      // then uintercept tail [d2_end, d2_end+N)
  int idx = blockIdx.x * 256 + threadIdx.x;
  int stride = gridDim.x * 256;
  for (int i = idx; i < n4; i += stride) {
    size_t e = 4 * (size_t)i;
    float4 v = make_float4(0.f, 0.f, 0.f, 0.f);
    if (e >= d2_end) {                                   // uintercept tail
      int b = (int)(e - d2_end);
      v.x = relu_vals(b + 0, cvec, lb_acc, ub_acc, raw_alpha).uinter;
      v.y = relu_vals(b + 1, cvec, lb_acc, ub_acc, raw_alpha).uinter;
      v.z = relu_vals(b + 2, cvec, lb_acc, ub_acc, raw_alpha).uinter;
      v.w = relu_vals(b + 3, cvec, lb_acc, ub_acc, raw_alpha).uinter;
    } else if (e < d1_end) {                             // diag(lslope)
      int r = (int)(e >> 12), c = (int)(e & 4095);
      if (r >= c && r < c + 4)
        (&v.x)[r - c] = relu_vals(r, cvec, lb_acc, ub_acc, raw_alpha).lslope;
    } else if (e >= d2_beg) {                            // diag(uslope)
      size_t e2 = e - d2_beg;
      int r = (int)(e2 >> 12), c = (int)(e2 & 4095);
      if (r >= c && r < c + 4)
        (&v.x)[r - c] = relu_vals(r, cvec, lb_acc, ub_acc, raw_alpha).uslope;
    }
    out[i] = v;
  }
}

extern "C" void kernel_launch(void* const* d_in, const int* in_sizes, int n_in,
                              void* d_out, int out_size, void* d_ws, size_t ws_size,
                              hipStream_t stream) {
  const float* raw_alpha = (const float*)d_in[0];
  const float* lb0 = (const float*)d_in[1];
  const float* ub0 = (const float*)d_in[2];
  const float* W1 = (const float*)d_in[3];
  const float* b1 = (const float*)d_in[4];
  const float* W2 = (const float*)d_in[5];
  const float* b2 = (const float*)d_in[6];

  float* cvec = (float*)d_ws;        // [N]
  float* lb_acc = cvec + N;          // [N]
  float* ub_acc = cvec + 2 * N;      // [N]

  // d_out (134 MB) doubles as bf16 scratch until the final fill
  unsigned short* W2b = (unsigned short*)d_out;       // [N*N] bf16, 32 MB
  unsigned short* W1Tb = W2b + (size_t)N * N;         // [N*N] bf16, 32 MB

  convert_w2<<<N, 256, 0, stream>>>(W2, b1, b2, W2b, cvec, lb_acc, ub_acc);
  transpose_w1<<<dim3(N / 64, N / 64), 256, 0, stream>>>(W1, W1Tb);
  gemm_bounds<<<dim3(N / BN, N / BM), 256, 0, stream>>>(W2b, W1Tb, lb0, ub0, lb_acc, ub_acc);
  int n4 = out_size / 4;
  fill_patch<<<8192, 256, 0, stream>>>((float4*)d_out, n4, cvec, lb_acc, ub_acc, raw_alpha);
}

// Round 6
// 418.097 us; speedup vs baseline: 1.0472x; 1.0472x over previous
//
#include <hip/hip_runtime.h>
#include <stdint.h>

#define N 4096
#define BM 128
#define BN 128
#define BK 128          // fp8 bytes: 128 B LDS row per tile row

#define QSCALE 256.0f           // W -> fp8 software scale (per tensor)
#define INV_QQ (1.0f / 65536.0f) // undo QSCALE^2 on S

typedef int v8i __attribute__((ext_vector_type(8)));
typedef float f32x16 __attribute__((ext_vector_type(16)));

union V8 { v8i v; uint4 h[2]; };

__device__ __forceinline__ void gload16(const unsigned char* g, unsigned char* l) {
  __builtin_amdgcn_global_load_lds(
      (const __attribute__((address_space(1))) unsigned int*)g,
      (__attribute__((address_space(3))) unsigned int*)l, 16, 0, 0);
}

// pack 4 floats -> 4 fp8 e4m3 bytes (OCP on gfx950)
__device__ __forceinline__ int pack4_fp8(float a, float b, float c, float d) {
  int r = __builtin_amdgcn_cvt_pk_fp8_f32(a, b, 0, false);
  r = __builtin_amdgcn_cvt_pk_fp8_f32(c, d, r, true);
  return r;
}

// ---- K1: t = W1 @ center (fp32, exact path), zero R_acc ----
__global__ __launch_bounds__(256) void matvec_w1(const float* __restrict__ W1,
                                                 const float* __restrict__ lb0,
                                                 const float* __restrict__ ub0,
                                                 float* __restrict__ tvec,
                                                 float* __restrict__ R_acc) {
  const int k = blockIdx.x;
  const int t = threadIdx.x;
  const float* row = W1 + (size_t)k * N;
  float dot = 0.f;
#pragma unroll
  for (int q = 0; q < 4; ++q) {
    int idx = (q * 256 + t) * 4;
    float4 w = *(const float4*)(row + idx);
    float4 l = *(const float4*)(lb0 + idx);
    float4 u = *(const float4*)(ub0 + idx);
    dot += w.x * 0.5f * (l.x + u.x) + w.y * 0.5f * (l.y + u.y)
         + w.z * 0.5f * (l.z + u.z) + w.w * 0.5f * (l.w + u.w);
  }
  __shared__ float red[256];
  red[t] = dot;
  __syncthreads();
  for (int s = 128; s > 0; s >>= 1) {
    if (t < s) red[t] += red[t + s];
    __syncthreads();
  }
  if (t == 0) {
    tvec[k] = red[0];
    R_acc[k] = 0.f;   // zero the |S| accumulator (gemm runs strictly after)
  }
}

// ---- K2: W2 -> fp8 (x256), fused c = b1@W2^T + b2 and Sc = W2 @ t ----
__global__ __launch_bounds__(256) void convert_w2(const float* __restrict__ W2,
                                                  const float* __restrict__ b1,
                                                  const float* __restrict__ b2,
                                                  const float* __restrict__ tvec,
                                                  unsigned char* __restrict__ W2q,
                                                  float* __restrict__ c,
                                                  float* __restrict__ Sc) {
  const int i = blockIdx.x;
  const int t = threadIdx.x;
  const float* row = W2 + (size_t)i * N;
  int* orow = (int*)(W2q + (size_t)i * N);
  float dotb = 0.f, dott = 0.f;
#pragma unroll
  for (int q = 0; q < 4; ++q) {
    int idx = (q * 256 + t) * 4;
    float4 w = *(const float4*)(row + idx);
    float4 b = *(const float4*)(b1 + idx);
    float4 tv = *(const float4*)(tvec + idx);
    dotb += w.x * b.x + w.y * b.y + w.z * b.z + w.w * b.w;
    dott += w.x * tv.x + w.y * tv.y + w.z * tv.z + w.w * tv.w;
    orow[q * 256 + t] = pack4_fp8(w.x * QSCALE, w.y * QSCALE, w.z * QSCALE, w.w * QSCALE);
  }
  __shared__ float red[512];
  red[t] = dotb;
  red[t + 256] = dott;
  __syncthreads();
  for (int s = 128; s > 0; s >>= 1) {
    if (t < s) { red[t] += red[t + s]; red[t + 256] += red[t + 256 + s]; }
    __syncthreads();
  }
  if (t == 0) {
    c[i] = red[0] + b2[i];
    Sc[i] = red[256];
  }
}

// ---- K3: W1 fp32 [k][j] -> fp8 W1T [j][k] (x256, LDS tile transpose) ----
__global__ __launch_bounds__(256) void transpose_w1(const float* __restrict__ W1,
                                                    unsigned char* __restrict__ W1T) {
  __shared__ float tile[64 * 65];
  const int t = threadIdx.x;
  const int j0 = blockIdx.x * 64, k0 = blockIdx.y * 64;
#pragma unroll
  for (int s = 0; s < 4; ++s) {
    int ck = s * 256 + t;
    int row = ck >> 4;             // k_local 0..63
    int col = (ck & 15) * 4;       // j_local
    float4 v = *(const float4*)(W1 + (size_t)(k0 + row) * N + j0 + col);
    float* d = &tile[row * 65 + col];
    d[0] = v.x; d[1] = v.y; d[2] = v.z; d[3] = v.w;
  }
  __syncthreads();
  int jl = t >> 2, ch = (t & 3) * 16;   // 16 consecutive k per thread
  float f[16];
#pragma unroll
  for (int m = 0; m < 16; ++m) f[m] = tile[(ch + m) * 65 + jl] * QSCALE;
  uint4 o;
  o.x = (unsigned)pack4_fp8(f[0], f[1], f[2], f[3]);
  o.y = (unsigned)pack4_fp8(f[4], f[5], f[6], f[7]);
  o.z = (unsigned)pack4_fp8(f[8], f[9], f[10], f[11]);
  o.w = (unsigned)pack4_fp8(f[12], f[13], f[14], f[15]);
  *(uint4*)(W1T + (size_t)(j0 + jl) * N + k0 + ch) = o;
}

// ---- K4: R_i = sum_j |(W2q @ W1Tq^T)_ij| * eps_j  via MX fp8 MFMA 32x32x64 ----
// all MX block-scales = 1.0 (0x7F); real scale (QSCALE^2) undone in fill_patch.
__global__ __launch_bounds__(256, 4) void gemm_absrow(const unsigned char* __restrict__ A,  // W2q [i][k]
                                                      const unsigned char* __restrict__ B,  // W1Tq [j][k]
                                                      const float* __restrict__ lb0,
                                                      const float* __restrict__ ub0,
                                                      float* __restrict__ R_acc) {
  __shared__ __align__(16) unsigned char As[BM * BK];   // 16 KB
  __shared__ __align__(16) unsigned char Bs[BN * BK];   // 16 KB
  const int t = threadIdx.x;
  const int lane = t & 63, w = t >> 6;
  const int wm = (w >> 1) * 64, wn = (w & 1) * 64;
  const int i0 = blockIdx.y * BM, j0 = blockIdx.x * BN;
  const int l31 = lane & 31, half = lane >> 5;

  f32x16 acc[2][2] = {};
  const int sc1 = 0x7F7F7F7F;  // E8M0 scale = 1.0 in all 4 bytes

  // staging: chunk c = p*256+t covers (row = c>>3, 16B piece c&7)
  const unsigned char* ga = A + (size_t)(i0 + (t >> 3)) * N + (t & 7) * 16;
  const unsigned char* gb = B + (size_t)(j0 + (t >> 3)) * N + (t & 7) * 16;

  for (int kt = 0; kt < N / BK; ++kt) {
    __syncthreads();
#pragma unroll
    for (int p = 0; p < 4; ++p) {
      gload16(ga + (size_t)(p * 32) * N, &As[(p * 256 + t) * 16]);
      gload16(gb + (size_t)(p * 32) * N, &Bs[(p * 256 + t) * 16]);
    }
    __syncthreads();
#pragma unroll
    for (int h = 0; h < 2; ++h) {               // two K=64 steps per BK=128
      const int koff = h * 64 + half * 32;      // lane's 32-byte k-slice
      V8 af[2], bfr[2];
#pragma unroll
      for (int tm = 0; tm < 2; ++tm) {
        const unsigned char* p = &As[(wm + tm * 32 + l31) * BK + koff];
        af[tm].h[0] = *(const uint4*)p;
        af[tm].h[1] = *(const uint4*)(p + 16);
      }
#pragma unroll
      for (int tn = 0; tn < 2; ++tn) {
        const unsigned char* p = &Bs[(wn + tn * 32 + l31) * BK + koff];
        bfr[tn].h[0] = *(const uint4*)p;
        bfr[tn].h[1] = *(const uint4*)(p + 16);
      }
#pragma unroll
      for (int tm = 0; tm < 2; ++tm)
#pragma unroll
        for (int tn = 0; tn < 2; ++tn)
          acc[tm][tn] = __builtin_amdgcn_mfma_scale_f32_32x32x64_f8f6f4(
              af[tm].v, bfr[tn].v, acc[tm][tn],
              0 /*cbsz: fp8*/, 0 /*blgp: fp8*/,
              0, sc1, 0, sc1);
    }
    ga += BK;
    gb += BK;
  }

  // epilogue: eps-weighted row L1 norm. C/D 32x32 layout:
  // col = lane&31, row = (r&3) + 8*(r>>2) + 4*(lane>>5)
  float epsv[2];
#pragma unroll
  for (int tn = 0; tn < 2; ++tn) {
    int j = j0 + wn + tn * 32 + l31;
    epsv[tn] = 0.5f * (ub0[j] - lb0[j]);
  }
#pragma unroll
  for (int tm = 0; tm < 2; ++tm) {
#pragma unroll
    for (int r = 0; r < 16; ++r) {
      float s = fabsf(acc[tm][0][r]) * epsv[0] + fabsf(acc[tm][1][r]) * epsv[1];
#pragma unroll
      for (int off = 1; off < 32; off <<= 1)   // reduce within each 32-lane half
        s += __shfl_xor(s, off, 64);
      if (l31 == 0) {
        int i = i0 + wm + tm * 32 + (r & 3) + 8 * (r >> 2) + 4 * half;
        atomicAdd(&R_acc[i], s);
      }
    }
  }
}

// ---- K5: fused zero-fill + DeepPolyReLU patch (single pass over 134 MB) ----
struct ReluVals { float lslope, uslope, uinter; };

__device__ __forceinline__ ReluVals relu_vals(int i,
                                              const float* __restrict__ cvec,
                                              const float* __restrict__ Sc,
                                              const float* __restrict__ R_acc,
                                              const float* __restrict__ raw_alpha) {
  float mid = Sc[i] + cvec[i];
  float rr = R_acc[i] * INV_QQ;
  float lb = mid - rr;
  float ub = mid + rr;
  float alpha = 1.f / (1.f + expf(-raw_alpha[i]));
  float denom = ub - lb;
  float slope = (denom == 0.f) ? 0.f : ub / denom;
  bool below = ub <= 0.f, above = lb >= 0.f;
  bool crossing = !(below || above);
  float base = above ? 1.f : 0.f;
  ReluVals v;
  v.uslope = crossing ? slope : base;
  v.uinter = crossing ? (1.f - slope) * ub : 0.f;
  float l1 = crossing ? 0.f : base;
  float l2 = crossing ? 1.f : base;
  v.lslope = alpha * l1 + (1.f - alpha) * l2;
  return v;
}

__global__ __launch_bounds__(256) void fill_patch(float4* __restrict__ out, int n4,
                                                  const float* __restrict__ cvec,
                                                  const float* __restrict__ Sc,
                                                  const float* __restrict__ R_acc,
                                                  const float* __restrict__ raw_alpha) {
  const size_t NN = (size_t)N * N;
  const size_t d1_end = NN;              // diag(lslope)
  const size_t d2_beg = NN + N;          // diag(uslope) after lintercept zeros
  const size_t d2_end = 2 * NN + N;      // uintercept tail
  int idx = blockIdx.x * 256 + threadIdx.x;
  int stride = gridDim.x * 256;
  for (int i = idx; i < n4; i += stride) {
    size_t e = 4 * (size_t)i;
    float4 v = make_float4(0.f, 0.f, 0.f, 0.f);
    if (e >= d2_end) {
      int b = (int)(e - d2_end);
      v.x = relu_vals(b + 0, cvec, Sc, R_acc, raw_alpha).uinter;
      v.y = relu_vals(b + 1, cvec, Sc, R_acc, raw_alpha).uinter;
      v.z = relu_vals(b + 2, cvec, Sc, R_acc, raw_alpha).uinter;
      v.w = relu_vals(b + 3, cvec, Sc, R_acc, raw_alpha).uinter;
    } else if (e < d1_end) {
      int r = (int)(e >> 12), c = (int)(e & 4095);
      if (r >= c && r < c + 4)
        (&v.x)[r - c] = relu_vals(r, cvec, Sc, R_acc, raw_alpha).lslope;
    } else if (e >= d2_beg) {
      size_t e2 = e - d2_beg;
      int r = (int)(e2 >> 12), c = (int)(e2 & 4095);
      if (r >= c && r < c + 4)
        (&v.x)[r - c] = relu_vals(r, cvec, Sc, R_acc, raw_alpha).uslope;
    }
    out[i] = v;
  }
}

extern "C" void kernel_launch(void* const* d_in, const int* in_sizes, int n_in,
                              void* d_out, int out_size, void* d_ws, size_t ws_size,
                              hipStream_t stream) {
  const float* raw_alpha = (const float*)d_in[0];
  const float* lb0 = (const float*)d_in[1];
  const float* ub0 = (const float*)d_in[2];
  const float* W1 = (const float*)d_in[3];
  const float* b1 = (const float*)d_in[4];
  const float* W2 = (const float*)d_in[5];
  const float* b2 = (const float*)d_in[6];

  float* tvec = (float*)d_ws;        // [N]  W1 @ center
  float* cvec = tvec + N;            // [N]  b1 @ W2^T + b2
  float* Sc = cvec + N;              // [N]  W2 @ tvec
  float* R_acc = Sc + N;             // [N]  eps-weighted row L1 of S (scaled)

  // d_out (134 MB) doubles as fp8 scratch until the final fill
  unsigned char* W2q = (unsigned char*)d_out;        // [N*N] fp8, 16 MB
  unsigned char* W1Tq = W2q + (size_t)N * N;         // [N*N] fp8, 16 MB

  matvec_w1<<<N, 256, 0, stream>>>(W1, lb0, ub0, tvec, R_acc);
  convert_w2<<<N, 256, 0, stream>>>(W2, b1, b2, tvec, W2q, cvec, Sc);
  transpose_w1<<<dim3(N / 64, N / 64), 256, 0, stream>>>(W1, W1Tq);
  gemm_absrow<<<dim3(N / BN, N / BM), 256, 0, stream>>>(W2q, W1Tq, lb0, ub0, R_acc);
  int n4 = out_size / 4;
  fill_patch<<<8192, 256, 0, stream>>>((float4*)d_out, n4, cvec, Sc, R_acc, raw_alpha);
}

// Round 7
// 373.654 us; speedup vs baseline: 1.1717x; 1.1189x over previous
//
#include <hip/hip_runtime.h>
#include <stdint.h>

#define N 4096
#define BM 128
#define BN 128
#define BK 128          // fp8 bytes of k per tile

// blocked scratch layout: addr = tile*524288 + kt*16384 + c*2048 + r*16
//   tile = row>>7, r = row&127, kt = kbyte>>7, c = (kbyte>>4)&7
#define TILE_BYTES 524288   // 128 rows * 4096 B
#define KT_BYTES   16384    // 8 chunks * 128 rows * 16 B

#define QSCALE 256.0f            // W -> fp8 software scale (per tensor)
#define INV_QQ (1.0f / 65536.0f) // undo QSCALE^2 on S

typedef int v8i __attribute__((ext_vector_type(8)));
typedef float f32x16 __attribute__((ext_vector_type(16)));

union V8 { v8i v; uint4 h[2]; };

__device__ __forceinline__ void gload16(const unsigned char* g, unsigned char* l) {
  __builtin_amdgcn_global_load_lds(
      (const __attribute__((address_space(1))) unsigned int*)g,
      (__attribute__((address_space(3))) unsigned int*)l, 16, 0, 0);
}

// pack 4 floats -> 4 fp8 e4m3 bytes (OCP on gfx950)
__device__ __forceinline__ int pack4_fp8(float a, float b, float c, float d) {
  int r = __builtin_amdgcn_cvt_pk_fp8_f32(a, b, 0, false);
  r = __builtin_amdgcn_cvt_pk_fp8_f32(c, d, r, true);
  return r;
}

// ---- K1: t = W1 @ center (fp32, exact path), zero R_acc ----
__global__ __launch_bounds__(256) void matvec_w1(const float* __restrict__ W1,
                                                 const float* __restrict__ lb0,
                                                 const float* __restrict__ ub0,
                                                 float* __restrict__ tvec,
                                                 float* __restrict__ R_acc) {
  const int k = blockIdx.x;
  const int t = threadIdx.x;
  const float* row = W1 + (size_t)k * N;
  float dot = 0.f;
#pragma unroll
  for (int q = 0; q < 4; ++q) {
    int idx = (q * 256 + t) * 4;
    float4 w = *(const float4*)(row + idx);
    float4 l = *(const float4*)(lb0 + idx);
    float4 u = *(const float4*)(ub0 + idx);
    dot += w.x * 0.5f * (l.x + u.x) + w.y * 0.5f * (l.y + u.y)
         + w.z * 0.5f * (l.z + u.z) + w.w * 0.5f * (l.w + u.w);
  }
  __shared__ float red[256];
  red[t] = dot;
  __syncthreads();
  for (int s = 128; s > 0; s >>= 1) {
    if (t < s) red[t] += red[t + s];
    __syncthreads();
  }
  if (t == 0) {
    tvec[k] = red[0];
    R_acc[k] = 0.f;   // zero the |S| accumulator (gemm runs strictly after)
  }
}

// ---- K2: W2 -> fp8 blocked scratch, fused c = b1@W2^T + b2 and Sc = W2 @ t ----
__global__ __launch_bounds__(256) void convert_w2(const float* __restrict__ W2,
                                                  const float* __restrict__ b1,
                                                  const float* __restrict__ b2,
                                                  const float* __restrict__ tvec,
                                                  unsigned char* __restrict__ W2q,
                                                  float* __restrict__ c,
                                                  float* __restrict__ Sc) {
  const int i = blockIdx.x;
  const int t = threadIdx.x;
  const float* row = W2 + (size_t)i * N;
  float dotb = 0.f, dott = 0.f;
  // thread t handles 16 consecutive k: one 16-B fp8 chunk
  const int k0 = t * 16;
  alignas(16) int packed[4];
#pragma unroll
  for (int q = 0; q < 4; ++q) {
    int idx = k0 + q * 4;
    float4 w = *(const float4*)(row + idx);
    float4 b = *(const float4*)(b1 + idx);
    float4 tv = *(const float4*)(tvec + idx);
    dotb += w.x * b.x + w.y * b.y + w.z * b.z + w.w * b.w;
    dott += w.x * tv.x + w.y * tv.y + w.z * tv.z + w.w * tv.w;
    packed[q] = pack4_fp8(w.x * QSCALE, w.y * QSCALE, w.z * QSCALE, w.w * QSCALE);
  }
  // blocked address: tile*524288 + t*2048 + r*16   (kt=t>>3, c=t&7 folded)
  *(uint4*)(W2q + (size_t)(i >> 7) * TILE_BYTES + (size_t)t * 2048 + (i & 127) * 16) =
      *(const uint4*)packed;

  __shared__ float red[512];
  red[t] = dotb;
  red[t + 256] = dott;
  __syncthreads();
  for (int s = 128; s > 0; s >>= 1) {
    if (t < s) { red[t] += red[t + s]; red[t + 256] += red[t + 256 + s]; }
    __syncthreads();
  }
  if (t == 0) {
    c[i] = red[0] + b2[i];
    Sc[i] = red[256];
  }
}

// ---- K3: W1 fp32 [k][j] -> fp8 W1T [j][k] blocked scratch (LDS transpose) ----
__global__ __launch_bounds__(256) void transpose_w1(const float* __restrict__ W1,
                                                    unsigned char* __restrict__ W1T) {
  __shared__ float tile[64 * 65];
  const int t = threadIdx.x;
  const int j0 = blockIdx.x * 64, k0 = blockIdx.y * 64;
#pragma unroll
  for (int s = 0; s < 4; ++s) {
    int ck = s * 256 + t;
    int row = ck >> 4;             // k_local 0..63
    int col = (ck & 15) * 4;       // j_local
    float4 v = *(const float4*)(W1 + (size_t)(k0 + row) * N + j0 + col);
    float* d = &tile[row * 65 + col];
    d[0] = v.x; d[1] = v.y; d[2] = v.z; d[3] = v.w;
  }
  __syncthreads();
  int jl = t >> 2, ch = (t & 3) * 16;   // 16 consecutive k per thread
  float f[16];
#pragma unroll
  for (int m = 0; m < 16; ++m) f[m] = tile[(ch + m) * 65 + jl] * QSCALE;
  uint4 o;
  o.x = (unsigned)pack4_fp8(f[0], f[1], f[2], f[3]);
  o.y = (unsigned)pack4_fp8(f[4], f[5], f[6], f[7]);
  o.z = (unsigned)pack4_fp8(f[8], f[9], f[10], f[11]);
  o.w = (unsigned)pack4_fp8(f[12], f[13], f[14], f[15]);
  int j = j0 + jl;
  int kb = k0 + ch;                     // k byte index
  *(uint4*)(W1T + (size_t)(j >> 7) * TILE_BYTES + (size_t)(kb >> 7) * KT_BYTES
            + (size_t)((kb >> 4) & 7) * 2048 + (j & 127) * 16) = o;
}

// ---- K4: R_i = sum_j |(W2q @ W1Tq^T)_ij| * eps_j  via MX fp8 MFMA 32x32x64 ----
// k-chunk-major LDS: As[c][r] at c*2048 + r*16 -> conflict-free ds_read_b128
// (fragment lanes stride 16 B: 8 lanes span all 32 banks).
__global__ __launch_bounds__(256, 4) void gemm_absrow(const unsigned char* __restrict__ A,  // W2q blocked
                                                      const unsigned char* __restrict__ B,  // W1Tq blocked
                                                      const float* __restrict__ lb0,
                                                      const float* __restrict__ ub0,
                                                      float* __restrict__ R_acc) {
  __shared__ __align__(16) unsigned char As[BM * BK];   // 16 KB
  __shared__ __align__(16) unsigned char Bs[BN * BK];   // 16 KB
  const int t = threadIdx.x;
  const int lane = t & 63, w = t >> 6;
  const int wm = (w >> 1) * 64, wn = (w & 1) * 64;
  const int i0 = blockIdx.y * BM, j0 = blockIdx.x * BN;
  const int l31 = lane & 31, half = lane >> 5;

  f32x16 acc[2][2] = {};
  const int sc1 = 0x7F7F7F7F;  // E8M0 scale = 1.0 in all 4 bytes

  // staging: slot s = p*256+t -> LDS s*16, global tile_base + kt*16384 + s*16
  // (wave reads 1024 contiguous global bytes, natural ascending order)
  const unsigned char* ga = A + (size_t)blockIdx.y * TILE_BYTES + t * 16;
  const unsigned char* gb = B + (size_t)blockIdx.x * TILE_BYTES + t * 16;

  for (int kt = 0; kt < N / BK; ++kt) {
    __syncthreads();
#pragma unroll
    for (int p = 0; p < 4; ++p) {
      gload16(ga + p * 4096, &As[(p * 256 + t) * 16]);
      gload16(gb + p * 4096, &Bs[(p * 256 + t) * 16]);
    }
    __syncthreads();
#pragma unroll
    for (int h = 0; h < 2; ++h) {               // two K=64 steps per BK=128
      const int c0 = h * 4 + half * 2;          // lane's first 16-B k-chunk
      V8 af[2], bfr[2];
#pragma unroll
      for (int tm = 0; tm < 2; ++tm) {
        const unsigned char* p = &As[c0 * 2048 + (wm + tm * 32 + l31) * 16];
        af[tm].h[0] = *(const uint4*)p;
        af[tm].h[1] = *(const uint4*)(p + 2048);   // next k-chunk
      }
#pragma unroll
      for (int tn = 0; tn < 2; ++tn) {
        const unsigned char* p = &Bs[c0 * 2048 + (wn + tn * 32 + l31) * 16];
        bfr[tn].h[0] = *(const uint4*)p;
        bfr[tn].h[1] = *(const uint4*)(p + 2048);
      }
#pragma unroll
      for (int tm = 0; tm < 2; ++tm)
#pragma unroll
        for (int tn = 0; tn < 2; ++tn)
          acc[tm][tn] = __builtin_amdgcn_mfma_scale_f32_32x32x64_f8f6f4(
              af[tm].v, bfr[tn].v, acc[tm][tn],
              0 /*cbsz: fp8*/, 0 /*blgp: fp8*/,
              0, sc1, 0, sc1);
    }
    ga += KT_BYTES;
    gb += KT_BYTES;
  }

  // epilogue: eps-weighted row L1 norm. C/D 32x32 layout:
  // col = lane&31, row = (r&3) + 8*(r>>2) + 4*(lane>>5)
  float epsv[2];
#pragma unroll
  for (int tn = 0; tn < 2; ++tn) {
    int j = j0 + wn + tn * 32 + l31;
    epsv[tn] = 0.5f * (ub0[j] - lb0[j]);
  }
#pragma unroll
  for (int tm = 0; tm < 2; ++tm) {
#pragma unroll
    for (int r = 0; r < 16; ++r) {
      float s = fabsf(acc[tm][0][r]) * epsv[0] + fabsf(acc[tm][1][r]) * epsv[1];
#pragma unroll
      for (int off = 1; off < 32; off <<= 1)   // reduce within each 32-lane half
        s += __shfl_xor(s, off, 64);
      if (l31 == 0) {
        int i = i0 + wm + tm * 32 + (r & 3) + 8 * (r >> 2) + 4 * half;
        atomicAdd(&R_acc[i], s);
      }
    }
  }
}

// ---- K5: fused zero-fill + DeepPolyReLU patch (single pass over 134 MB) ----
struct ReluVals { float lslope, uslope, uinter; };

__device__ __forceinline__ ReluVals relu_vals(int i,
                                              const float* __restrict__ cvec,
                                              const float* __restrict__ Sc,
                                              const float* __restrict__ R_acc,
                                              const float* __restrict__ raw_alpha) {
  float mid = Sc[i] + cvec[i];
  float rr = R_acc[i] * INV_QQ;
  float lb = mid - rr;
  float ub = mid + rr;
  float alpha = 1.f / (1.f + expf(-raw_alpha[i]));
  float denom = ub - lb;
  float slope = (denom == 0.f) ? 0.f : ub / denom;
  bool below = ub <= 0.f, above = lb >= 0.f;
  bool crossing = !(below || above);
  float base = above ? 1.f : 0.f;
  ReluVals v;
  v.uslope = crossing ? slope : base;
  v.uinter = crossing ? (1.f - slope) * ub : 0.f;
  float l1 = crossing ? 0.f : base;
  float l2 = crossing ? 1.f : base;
  v.lslope = alpha * l1 + (1.f - alpha) * l2;
  return v;
}

__global__ __launch_bounds__(256) void fill_patch(float4* __restrict__ out, int n4,
                                                  const float* __restrict__ cvec,
                                                  const float* __restrict__ Sc,
                                                  const float* __restrict__ R_acc,
                                                  const float* __restrict__ raw_alpha) {
  const size_t NN = (size_t)N * N;
  const size_t d1_end = NN;              // diag(lslope)
  const size_t d2_beg = NN + N;          // diag(uslope) after lintercept zeros
  const size_t d2_end = 2 * NN + N;      // uintercept tail
  int idx = blockIdx.x * 256 + threadIdx.x;
  int stride = gridDim.x * 256;
  for (int i = idx; i < n4; i += stride) {
    size_t e = 4 * (size_t)i;
    float4 v = make_float4(0.f, 0.f, 0.f, 0.f);
    if (e >= d2_end) {
      int b = (int)(e - d2_end);
      v.x = relu_vals(b + 0, cvec, Sc, R_acc, raw_alpha).uinter;
      v.y = relu_vals(b + 1, cvec, Sc, R_acc, raw_alpha).uinter;
      v.z = relu_vals(b + 2, cvec, Sc, R_acc, raw_alpha).uinter;
      v.w = relu_vals(b + 3, cvec, Sc, R_acc, raw_alpha).uinter;
    } else if (e < d1_end) {
      int r = (int)(e >> 12), c = (int)(e & 4095);
      if (r >= c && r < c + 4)
        (&v.x)[r - c] = relu_vals(r, cvec, Sc, R_acc, raw_alpha).lslope;
    } else if (e >= d2_beg) {
      size_t e2 = e - d2_beg;
      int r = (int)(e2 >> 12), c = (int)(e2 & 4095);
      if (r >= c && r < c + 4)
        (&v.x)[r - c] = relu_vals(r, cvec, Sc, R_acc, raw_alpha).uslope;
    }
    out[i] = v;
  }
}

extern "C" void kernel_launch(void* const* d_in, const int* in_sizes, int n_in,
                              void* d_out, int out_size, void* d_ws, size_t ws_size,
                              hipStream_t stream) {
  const float* raw_alpha = (const float*)d_in[0];
  const float* lb0 = (const float*)d_in[1];
  const float* ub0 = (const float*)d_in[2];
  const float* W1 = (const float*)d_in[3];
  const float* b1 = (const float*)d_in[4];
  const float* W2 = (const float*)d_in[5];
  const float* b2 = (const float*)d_in[6];

  float* tvec = (float*)d_ws;        // [N]  W1 @ center
  float* cvec = tvec + N;            // [N]  b1 @ W2^T + b2
  float* Sc = cvec + N;              // [N]  W2 @ tvec
  float* R_acc = Sc + N;             // [N]  eps-weighted row L1 of S (scaled)

  // d_out (134 MB) doubles as fp8 blocked scratch until the final fill
  unsigned char* W2q = (unsigned char*)d_out;        // [N*N] fp8 blocked, 16 MB
  unsigned char* W1Tq = W2q + (size_t)N * N;         // [N*N] fp8 blocked, 16 MB

  matvec_w1<<<N, 256, 0, stream>>>(W1, lb0, ub0, tvec, R_acc);
  convert_w2<<<N, 256, 0, stream>>>(W2, b1, b2, tvec, W2q, cvec, Sc);
  transpose_w1<<<dim3(N / 64, N / 64), 256, 0, stream>>>(W1, W1Tq);
  gemm_absrow<<<dim3(N / BN, N / BM), 256, 0, stream>>>(W2q, W1Tq, lb0, ub0, R_acc);
  int n4 = out_size / 4;
  fill_patch<<<8192, 256, 0, stream>>>((float4*)d_out, n4, cvec, Sc, R_acc, raw_alpha);
}

// Round 8
// 352.989 us; speedup vs baseline: 1.2403x; 1.0585x over previous
//
#include <hip/hip_runtime.h>
#include <stdint.h>

#define N 4096
#define BM 128
#define BN 128
#define BK 128          // fp8 bytes of k per tile

// blocked scratch layout: addr = tile*524288 + kt*16384 + c*2048 + r*16
//   tile = row>>7, r = row&127, kt = kbyte>>7, c = (kbyte>>4)&7
#define TILE_BYTES 524288   // 128 rows * 4096 B
#define KT_BYTES   16384    // 8 chunks * 128 rows * 16 B

#define QSCALE 256.0f            // W -> fp8 software scale (per tensor)
#define INV_QQ (1.0f / 65536.0f) // undo QSCALE^2 on S

typedef int v8i __attribute__((ext_vector_type(8)));
typedef float f32x16 __attribute__((ext_vector_type(16)));

union V8 { v8i v; uint4 h[2]; };

__device__ __forceinline__ void gload16(const unsigned char* g, unsigned char* l) {
  __builtin_amdgcn_global_load_lds(
      (const __attribute__((address_space(1))) unsigned int*)g,
      (__attribute__((address_space(3))) unsigned int*)l, 16, 0, 0);
}

// pack 4 floats -> 4 fp8 e4m3 bytes (OCP on gfx950)
__device__ __forceinline__ int pack4_fp8(float a, float b, float c, float d) {
  int r = __builtin_amdgcn_cvt_pk_fp8_f32(a, b, 0, false);
  r = __builtin_amdgcn_cvt_pk_fp8_f32(c, d, r, true);
  return r;
}

// ---- K1: W1 fp32 [k][j] -> fp8 W1T blocked  +  tvec[k] += W1[k][:] . center ----
__global__ __launch_bounds__(256) void prep_w1(const float* __restrict__ W1,
                                               const float* __restrict__ lb0,
                                               const float* __restrict__ ub0,
                                               unsigned char* __restrict__ W1T,
                                               float* __restrict__ tvec) {
  __shared__ float tile[64 * 65];
  __shared__ float tdot[64];
  const int t = threadIdx.x;
  const int j0 = blockIdx.x * 64, k0 = blockIdx.y * 64;
  if (t < 64) tdot[t] = 0.f;
  __syncthreads();
#pragma unroll
  for (int s = 0; s < 4; ++s) {
    int ck = s * 256 + t;
    int row = ck >> 4;             // k_local 0..63
    int col = (ck & 15) * 4;       // j_local
    float4 v = *(const float4*)(W1 + (size_t)(k0 + row) * N + j0 + col);
    float4 l = *(const float4*)(lb0 + j0 + col);
    float4 u = *(const float4*)(ub0 + j0 + col);
    float part = v.x * 0.5f * (l.x + u.x) + v.y * 0.5f * (l.y + u.y)
               + v.z * 0.5f * (l.z + u.z) + v.w * 0.5f * (l.w + u.w);
    atomicAdd(&tdot[row], part);
    float* d = &tile[row * 65 + col];
    d[0] = v.x; d[1] = v.y; d[2] = v.z; d[3] = v.w;
  }
  __syncthreads();
  if (t < 64) atomicAdd(&tvec[k0 + t], tdot[t]);
  int jl = t >> 2, ch = (t & 3) * 16;   // 16 consecutive k per thread
  float f[16];
#pragma unroll
  for (int m = 0; m < 16; ++m) f[m] = tile[(ch + m) * 65 + jl] * QSCALE;
  uint4 o;
  o.x = (unsigned)pack4_fp8(f[0], f[1], f[2], f[3]);
  o.y = (unsigned)pack4_fp8(f[4], f[5], f[6], f[7]);
  o.z = (unsigned)pack4_fp8(f[8], f[9], f[10], f[11]);
  o.w = (unsigned)pack4_fp8(f[12], f[13], f[14], f[15]);
  int j = j0 + jl;
  int kb = k0 + ch;                     // k byte index
  *(uint4*)(W1T + (size_t)(j >> 7) * TILE_BYTES + (size_t)(kb >> 7) * KT_BYTES
            + (size_t)((kb >> 4) & 7) * 2048 + (j & 127) * 16) = o;
}

// ---- K2: W2 -> fp8 blocked (coalesced panel writes),
//          cvec[i] += b1 . W2[i,:],  Sc[i] += tvec . W2[i,:]  (per 128-k panel) ----
__global__ __launch_bounds__(256) void convert_w2(const float* __restrict__ W2,
                                                  const float* __restrict__ b1,
                                                  const float* __restrict__ tvec,
                                                  unsigned char* __restrict__ W2q,
                                                  float* __restrict__ cvec,
                                                  float* __restrict__ Sc) {
  const int t = threadIdx.x;
  const int i0 = blockIdx.y * 128;       // row tile
  const int k0 = blockIdx.x * 128;       // k panel
  const int r = t & 127;                 // row within tile
  const int h = t >> 7;                  // 0/1: chunk parity
  unsigned char* panel = W2q + (size_t)blockIdx.y * TILE_BYTES
                       + (size_t)blockIdx.x * KT_BYTES;
  float dotb = 0.f, dott = 0.f;
#pragma unroll
  for (int q = 0; q < 4; ++q) {
    int c = 2 * q + h;                   // 16-B k-chunk index 0..7
    const float* p = W2 + (size_t)(i0 + r) * N + k0 + c * 16;
    alignas(16) int packed[4];
#pragma unroll
    for (int m = 0; m < 4; ++m) {
      float4 w = *(const float4*)(p + m * 4);
      float4 b = *(const float4*)(b1 + k0 + c * 16 + m * 4);
      float4 tv = *(const float4*)(tvec + k0 + c * 16 + m * 4);
      dotb += w.x * b.x + w.y * b.y + w.z * b.z + w.w * b.w;
      dott += w.x * tv.x + w.y * tv.y + w.z * tv.z + w.w * tv.w;
      packed[m] = pack4_fp8(w.x * QSCALE, w.y * QSCALE, w.z * QSCALE, w.w * QSCALE);
    }
    // consecutive lanes -> consecutive r -> contiguous 16-B stores
    *(uint4*)(panel + (size_t)c * 2048 + r * 16) = *(const uint4*)packed;
  }
  __shared__ float redb[256], redt[256];
  redb[t] = dotb;
  redt[t] = dott;
  __syncthreads();
  if (t < 128) {
    float vb = redb[t] + redb[t + 128];
    float vt = redt[t] + redt[t + 128];
    atomicAdd(&cvec[i0 + t], vb);
    atomicAdd(&Sc[i0 + t], vt);
  }
}

// ---- K3: R_i = sum_j |(W2q @ W1Tq^T)_ij| * eps_j  via MX fp8 MFMA 32x32x64 ----
// k-chunk-major LDS: As[c][r] at c*2048 + r*16 -> conflict-free ds_read_b128
__global__ __launch_bounds__(256, 4) void gemm_absrow(const unsigned char* __restrict__ A,  // W2q blocked
                                                      const unsigned char* __restrict__ B,  // W1Tq blocked
                                                      const float* __restrict__ lb0,
                                                      const float* __restrict__ ub0,
                                                      float* __restrict__ R_acc) {
  __shared__ __align__(16) unsigned char As[BM * BK];   // 16 KB
  __shared__ __align__(16) unsigned char Bs[BN * BK];   // 16 KB
  const int t = threadIdx.x;
  const int lane = t & 63, w = t >> 6;
  const int wm = (w >> 1) * 64, wn = (w & 1) * 64;
  const int i0 = blockIdx.y * BM, j0 = blockIdx.x * BN;
  const int l31 = lane & 31, half = lane >> 5;

  f32x16 acc[2][2] = {};
  const int sc1 = 0x7F7F7F7F;  // E8M0 scale = 1.0 in all 4 bytes

  const unsigned char* ga = A + (size_t)blockIdx.y * TILE_BYTES + t * 16;
  const unsigned char* gb = B + (size_t)blockIdx.x * TILE_BYTES + t * 16;

  for (int kt = 0; kt < N / BK; ++kt) {
    __syncthreads();
#pragma unroll
    for (int p = 0; p < 4; ++p) {
      gload16(ga + p * 4096, &As[(p * 256 + t) * 16]);
      gload16(gb + p * 4096, &Bs[(p * 256 + t) * 16]);
    }
    __syncthreads();
#pragma unroll
    for (int h = 0; h < 2; ++h) {               // two K=64 steps per BK=128
      const int c0 = h * 4 + half * 2;          // lane's first 16-B k-chunk
      V8 af[2], bfr[2];
#pragma unroll
      for (int tm = 0; tm < 2; ++tm) {
        const unsigned char* p = &As[c0 * 2048 + (wm + tm * 32 + l31) * 16];
        af[tm].h[0] = *(const uint4*)p;
        af[tm].h[1] = *(const uint4*)(p + 2048);   // next k-chunk
      }
#pragma unroll
      for (int tn = 0; tn < 2; ++tn) {
        const unsigned char* p = &Bs[c0 * 2048 + (wn + tn * 32 + l31) * 16];
        bfr[tn].h[0] = *(const uint4*)p;
        bfr[tn].h[1] = *(const uint4*)(p + 2048);
      }
#pragma unroll
      for (int tm = 0; tm < 2; ++tm)
#pragma unroll
        for (int tn = 0; tn < 2; ++tn)
          acc[tm][tn] = __builtin_amdgcn_mfma_scale_f32_32x32x64_f8f6f4(
              af[tm].v, bfr[tn].v, acc[tm][tn],
              0 /*cbsz: fp8*/, 0 /*blgp: fp8*/,
              0, sc1, 0, sc1);
    }
    ga += KT_BYTES;
    gb += KT_BYTES;
  }

  // epilogue: eps-weighted row L1 norm. C/D 32x32 layout:
  // col = lane&31, row = (r&3) + 8*(r>>2) + 4*(lane>>5)
  float epsv[2];
#pragma unroll
  for (int tn = 0; tn < 2; ++tn) {
    int j = j0 + wn + tn * 32 + l31;
    epsv[tn] = 0.5f * (ub0[j] - lb0[j]);
  }
#pragma unroll
  for (int tm = 0; tm < 2; ++tm) {
#pragma unroll
    for (int r = 0; r < 16; ++r) {
      float s = fabsf(acc[tm][0][r]) * epsv[0] + fabsf(acc[tm][1][r]) * epsv[1];
#pragma unroll
      for (int off = 1; off < 32; off <<= 1)   // reduce within each 32-lane half
        s += __shfl_xor(s, off, 64);
      if (l31 == 0) {
        int i = i0 + wm + tm * 32 + (r & 3) + 8 * (r >> 2) + 4 * half;
        atomicAdd(&R_acc[i], s);
      }
    }
  }
}

// ---- K4: fused zero-fill + DeepPolyReLU patch (single pass over 134 MB) ----
struct ReluVals { float lslope, uslope, uinter; };

__device__ __forceinline__ ReluVals relu_vals(int i,
                                              const float* __restrict__ cvec,
                                              const float* __restrict__ Sc,
                                              const float* __restrict__ b2,
                                              const float* __restrict__ R_acc,
                                              const float* __restrict__ raw_alpha) {
  float mid = Sc[i] + cvec[i] + b2[i];
  float rr = R_acc[i] * INV_QQ;
  float lb = mid - rr;
  float ub = mid + rr;
  float alpha = 1.f / (1.f + expf(-raw_alpha[i]));
  float denom = ub - lb;
  float slope = (denom == 0.f) ? 0.f : ub / denom;
  bool below = ub <= 0.f, above = lb >= 0.f;
  bool crossing = !(below || above);
  float base = above ? 1.f : 0.f;
  ReluVals v;
  v.uslope = crossing ? slope : base;
  v.uinter = crossing ? (1.f - slope) * ub : 0.f;
  float l1 = crossing ? 0.f : base;
  float l2 = crossing ? 1.f : base;
  v.lslope = alpha * l1 + (1.f - alpha) * l2;
  return v;
}

__global__ __launch_bounds__(256) void fill_patch(float4* __restrict__ out, int n4,
                                                  const float* __restrict__ cvec,
                                                  const float* __restrict__ Sc,
                                                  const float* __restrict__ b2,
                                                  const float* __restrict__ R_acc,
                                                  const float* __restrict__ raw_alpha) {
  const size_t NN = (size_t)N * N;
  const size_t d1_end = NN;              // diag(lslope)
  const size_t d2_beg = NN + N;          // diag(uslope) after lintercept zeros
  const size_t d2_end = 2 * NN + N;      // uintercept tail
  int idx = blockIdx.x * 256 + threadIdx.x;
  int stride = gridDim.x * 256;
  for (int i = idx; i < n4; i += stride) {
    size_t e = 4 * (size_t)i;
    float4 v = make_float4(0.f, 0.f, 0.f, 0.f);
    if (e >= d2_end) {
      int b = (int)(e - d2_end);
      v.x = relu_vals(b + 0, cvec, Sc, b2, R_acc, raw_alpha).uinter;
      v.y = relu_vals(b + 1, cvec, Sc, b2, R_acc, raw_alpha).uinter;
      v.z = relu_vals(b + 2, cvec, Sc, b2, R_acc, raw_alpha).uinter;
      v.w = relu_vals(b + 3, cvec, Sc, b2, R_acc, raw_alpha).uinter;
    } else if (e < d1_end) {
      int r = (int)(e >> 12), c = (int)(e & 4095);
      if (r >= c && r < c + 4)
        (&v.x)[r - c] = relu_vals(r, cvec, Sc, b2, R_acc, raw_alpha).lslope;
    } else if (e >= d2_beg) {
      size_t e2 = e - d2_beg;
      int r = (int)(e2 >> 12), c = (int)(e2 & 4095);
      if (r >= c && r < c + 4)
        (&v.x)[r - c] = relu_vals(r, cvec, Sc, b2, R_acc, raw_alpha).uslope;
    }
    out[i] = v;
  }
}

extern "C" void kernel_launch(void* const* d_in, const int* in_sizes, int n_in,
                              void* d_out, int out_size, void* d_ws, size_t ws_size,
                              hipStream_t stream) {
  const float* raw_alpha = (const float*)d_in[0];
  const float* lb0 = (const float*)d_in[1];
  const float* ub0 = (const float*)d_in[2];
  const float* W1 = (const float*)d_in[3];
  const float* b1 = (const float*)d_in[4];
  const float* W2 = (const float*)d_in[5];
  const float* b2 = (const float*)d_in[6];

  float* tvec = (float*)d_ws;        // [N]  W1 @ center         (atomic-accum)
  float* cvec = tvec + N;            // [N]  b1 @ W2^T           (atomic-accum)
  float* Sc = cvec + N;              // [N]  W2 @ tvec           (atomic-accum)
  float* R_acc = Sc + N;             // [N]  eps-weighted row L1 (atomic-accum)

  // d_out (134 MB) doubles as fp8 blocked scratch until the final fill
  unsigned char* W2q = (unsigned char*)d_out;        // [N*N] fp8 blocked, 16 MB
  unsigned char* W1Tq = W2q + (size_t)N * N;         // [N*N] fp8 blocked, 16 MB

  (void)hipMemsetAsync(d_ws, 0, 4 * N * sizeof(float), stream);
  prep_w1<<<dim3(N / 64, N / 64), 256, 0, stream>>>(W1, lb0, ub0, W1Tq, tvec);
  convert_w2<<<dim3(N / 128, N / 128), 256, 0, stream>>>(W2, b1, tvec, W2q, cvec, Sc);
  gemm_absrow<<<dim3(N / BN, N / BM), 256, 0, stream>>>(W2q, W1Tq, lb0, ub0, R_acc);
  int n4 = out_size / 4;
  fill_patch<<<8192, 256, 0, stream>>>((float4*)d_out, n4, cvec, Sc, b2, R_acc, raw_alpha);
}